// Round 10
// baseline (119.579 us; speedup 1.0000x reference)
//
#include <hip/hip_runtime.h>
#include <hip/hip_bf16.h>

// NeuralAdditiveModel: out[b] = sum_f( W3[f] . relu(W2[f]^T relu(x[b,f]*W1[f]+b1[f]) + b2[f]) + b3[f] ) + bias
// B=8192, F=128, S=128, H1=64, O=1
#define B_ 8192
#define F_ 128
#define S_ 128
#define H_ 64

typedef __attribute__((ext_vector_type(4))) float f32x4;
typedef __attribute__((ext_vector_type(8))) short bf16x8;  // 8 bf16 in 4 VGPRs

__global__ __launch_bounds__(256) void nam_init(float* __restrict__ out,
                                                const float* __restrict__ bias) {
    int i = blockIdx.x * 256 + threadIdx.x;
    if (i < B_) out[i] = bias[0];
}

static __device__ __forceinline__ short f2bf(float v) {
    __hip_bfloat16 t = __float2bfloat16(v);   // RNE
    return __builtin_bit_cast(short, t);
}

// Pre-pass 1: W2 [F][S][H] fp32 -> bf16 in MFMA A-frag order [f][kk][m][lane][8].
__global__ __launch_bounds__(256) void nam_prep(const float* __restrict__ W2,
                                                bf16x8* __restrict__ W2bf) {
    const int idx = blockIdx.x * 256 + threadIdx.x;   // [f][kk][m][l]
    const int l   = idx & 63;
    const int m   = (idx >> 6) & 3;
    const int kk  = (idx >> 8) & 3;
    const int f   = idx >> 10;
    const int l16 = l & 15, lg = l >> 4;

    const float* __restrict__ src =
        W2 + ((size_t)f * S_ + kk * 32 + lg * 8) * H_ + m * 16 + l16;
    bf16x8 v;
#pragma unroll
    for (int j = 0; j < 8; ++j) v[j] = f2bf(src[j * H_]);
    W2bf[idx] = v;
}

// Pre-pass 2: x [B][F] -> xT [F][B] via LDS 32x32 tile (coalesced read AND write).
__global__ __launch_bounds__(256) void nam_xt(const float* __restrict__ x,
                                              float* __restrict__ xT) {
    __shared__ float t[32][33];                 // +1 pad: no bank conflicts
    const int li = threadIdx.x & 31;
    const int wi = threadIdx.x >> 5;            // 8 row-groups
    const int b0 = (blockIdx.x & 255) * 32;     // B/32 = 256 tiles
    const int f0 = (blockIdx.x >> 8) * 32;      // F/32 = 4 tiles
#pragma unroll
    for (int r = wi; r < 32; r += 8)
        t[r][li] = x[(size_t)(b0 + r) * F_ + f0 + li];
    __syncthreads();
#pragma unroll
    for (int r = wi; r < 32; r += 8)
        xT[(size_t)(f0 + r) * B_ + b0 + li] = t[li][r];
}

// One block: feature f x 128 batch rows; 4 waves x (32 b-cols, 64 h, K=128).
// h2^T = W2^T(64x128) * h1^T(128x32) per wave; C layout: col(lane&15)=batch, row=h.
// acc = 32 regs/lane; K-loop NOT unrolled (only 4 A-frags live) -> high occupancy.
__global__ __launch_bounds__(256, 4) void nam_mfma(
    const float* __restrict__ x,        // [B,F]   (fallback path)
    const float* __restrict__ xT,       // [F,B]   (preferred; may be null)
    const float* __restrict__ W1,       // [F,S]
    const float* __restrict__ b1,       // [F,S]
    const bf16x8* __restrict__ W2bf,    // [F][4][4][64] frags
    const float* __restrict__ b2,       // [F,H]
    const float* __restrict__ W3,       // [F,H] (O=1)
    const float* __restrict__ b3,       // [F]
    float* __restrict__ out)            // [B]
{
    const int f   = blockIdx.x >> 6;    // 64 consecutive blocks share f
    const int bt  = blockIdx.x & 63;
    const int tid = threadIdx.x;
    const int w   = tid >> 6;
    const int l   = tid & 63;
    const int l16 = l & 15;
    const int lg  = l >> 4;

    const int bbase = bt * 128 + w * 32;

    const float* __restrict__ W1f = W1 + f * S_;
    const float* __restrict__ b1f = b1 + f * S_;
    const bf16x8* __restrict__ W2f = W2bf + (size_t)f * 16 * 64 + l;

    float xv0, xv1;
    if (xT) {                                       // coalesced: 64B line per 16-lane group
        xv0 = xT[(size_t)f * B_ + bbase + l16];
        xv1 = xT[(size_t)f * B_ + bbase + 16 + l16];
    } else {                                        // strided fallback
        xv0 = x[(size_t)(bbase + l16) * F_ + f];
        xv1 = x[(size_t)(bbase + 16 + l16) * F_ + f];
    }

    f32x4 acc[4][2];
#pragma unroll
    for (int m = 0; m < 4; ++m) {
        acc[m][0] = (f32x4){0.f, 0.f, 0.f, 0.f};
        acc[m][1] = (f32x4){0.f, 0.f, 0.f, 0.f};
    }

#pragma unroll 1
    for (int kk = 0; kk < 4; ++kk) {
        // Issue A-frag loads first (independent of bfrag VALU below -> latency overlap)
        bf16x8 afrag[4];
#pragma unroll
        for (int m = 0; m < 4; ++m)
            afrag[m] = W2f[(kk * 4 + m) * 64];

        const int s0 = kk * 32 + lg * 8;
        const f32x4 w1a = *(const f32x4*)(W1f + s0);
        const f32x4 w1b = *(const f32x4*)(W1f + s0 + 4);
        const f32x4 b1a = *(const f32x4*)(b1f + s0);
        const f32x4 b1b = *(const f32x4*)(b1f + s0 + 4);

        // B-frags: h1^T[k=s][col=b] = relu(x[b]*W1[s]+b1[s]) in bf16
        bf16x8 bf0, bf1;
#pragma unroll
        for (int j = 0; j < 4; ++j) {
            bf0[j]     = f2bf(fmaxf(fmaf(xv0, w1a[j], b1a[j]), 0.f));
            bf0[j + 4] = f2bf(fmaxf(fmaf(xv0, w1b[j], b1b[j]), 0.f));
            bf1[j]     = f2bf(fmaxf(fmaf(xv1, w1a[j], b1a[j]), 0.f));
            bf1[j + 4] = f2bf(fmaxf(fmaf(xv1, w1b[j], b1b[j]), 0.f));
        }

#pragma unroll
        for (int m = 0; m < 4; ++m) {
            acc[m][0] = __builtin_amdgcn_mfma_f32_16x16x32_bf16(afrag[m], bf0, acc[m][0], 0, 0, 0);
            acc[m][1] = __builtin_amdgcn_mfma_f32_16x16x32_bf16(afrag[m], bf1, acc[m][1], 0, 0, 0);
        }
    }

    // Epilogue: fo[b] = sum_h relu(h2+b2)*W3 (+b3); lane h = m*16+lg*4+r
    const float* __restrict__ b2f = b2 + f * H_;
    const float* __restrict__ W3f = W3 + f * H_;
    const float b3f = b3[f];

    float fo0 = 0.f, fo1 = 0.f;
#pragma unroll
    for (int m = 0; m < 4; ++m) {
        const f32x4 b2v = *(const f32x4*)(b2f + m * 16 + lg * 4);
        const f32x4 w3v = *(const f32x4*)(W3f + m * 16 + lg * 4);
#pragma unroll
        for (int r = 0; r < 4; ++r) {
            fo0 = fmaf(fmaxf(acc[m][0][r] + b2v[r], 0.f), w3v[r], fo0);
            fo1 = fmaf(fmaxf(acc[m][1][r] + b2v[r], 0.f), w3v[r], fo1);
        }
    }
    fo0 += __shfl_xor(fo0, 16);
    fo0 += __shfl_xor(fo0, 32);
    fo1 += __shfl_xor(fo1, 16);
    fo1 += __shfl_xor(fo1, 32);
    if (lg == 0) {
        atomicAdd(&out[bbase + l16], fo0 + b3f);
        atomicAdd(&out[bbase + 16 + l16], fo1 + b3f);
    }
}

extern "C" void kernel_launch(void* const* d_in, const int* in_sizes, int n_in,
                              void* d_out, int out_size, void* d_ws, size_t ws_size,
                              hipStream_t stream) {
    const float* x    = (const float*)d_in[0];
    const float* W1   = (const float*)d_in[1];
    const float* b1   = (const float*)d_in[2];
    const float* W2   = (const float*)d_in[3];
    const float* b2   = (const float*)d_in[4];
    const float* W3   = (const float*)d_in[5];
    const float* b3   = (const float*)d_in[6];
    const float* bias = (const float*)d_in[7];
    float* out = (float*)d_out;

    bf16x8* W2bf = (bf16x8*)d_ws;                       // 2 MB: [F][4][4][64] frags
    const size_t W2BF_BYTES = (size_t)F_ * 16 * 64 * 16;
    const size_t XT_BYTES   = (size_t)F_ * B_ * 4;      // 4 MB
    float* xT = (ws_size >= W2BF_BYTES + XT_BYTES)
                    ? (float*)((char*)d_ws + W2BF_BYTES) : nullptr;

    nam_init<<<(B_ + 255) / 256, 256, 0, stream>>>(out, bias);
    nam_prep<<<(F_ * 16 * 64) / 256, 256, 0, stream>>>(W2, W2bf);
    if (xT)
        nam_xt<<<(B_ / 32) * (F_ / 32), 256, 0, stream>>>(x, xT);
    nam_mfma<<<F_ * (B_ / 128), 256, 0, stream>>>(x, xT, W1, b1, W2bf, b2, W3, b3, out);
}

// Round 11
// 96.606 us; speedup vs baseline: 1.2378x; 1.2378x over previous
//
#include <hip/hip_runtime.h>
#include <hip/hip_bf16.h>

// NeuralAdditiveModel: out[b] = sum_f( W3[f] . relu(W2[f]^T relu(x[b,f]*W1[f]+b1[f]) + b2[f]) + b3[f] ) + bias
// B=8192, F=128, S=128, H1=64, O=1
#define B_ 8192
#define F_ 128
#define S_ 128
#define H_ 64
#define NCHUNK 8                      // b-chunks per feature; grid = F_*NCHUNK = 1024

typedef __attribute__((ext_vector_type(4))) float f32x4;
typedef __attribute__((ext_vector_type(8))) short bf16x8;  // 8 bf16 in 4 VGPRs

static __device__ __forceinline__ short f2bf(float v) {
    __hip_bfloat16 t = __float2bfloat16(v);   // RNE
    return __builtin_bit_cast(short, t);
}

// ---- Prologue: ONE dispatch doing init + W2 prep + x transpose (branch on blockIdx) ----
//  blocks [0,32)        : out[i] = bias[0]
//  blocks [32,544)      : W2 [F][S][H] fp32 -> bf16 MFMA A-frag order [f][kk][m][lane][8]
//  blocks [544,1568)    : x [B][F] -> xT [F][B] via padded LDS 32x32 tile
__global__ __launch_bounds__(256) void nam_prologue(
    const float* __restrict__ bias, float* __restrict__ out,
    const float* __restrict__ W2,   bf16x8* __restrict__ W2bf,
    const float* __restrict__ x,    float* __restrict__ xT)
{
    __shared__ float t[32][33];
    const int blk = blockIdx.x;
    if (blk < 32) {
        int i = blk * 256 + threadIdx.x;
        out[i] = bias[0];
    } else if (blk < 544) {
        const int idx = (blk - 32) * 256 + threadIdx.x;   // [f][kk][m][l]
        const int l   = idx & 63;
        const int m   = (idx >> 6) & 3;
        const int kk  = (idx >> 8) & 3;
        const int f   = idx >> 10;
        const int l16 = l & 15, lg = l >> 4;
        const float* __restrict__ src =
            W2 + ((size_t)f * S_ + kk * 32 + lg * 8) * H_ + m * 16 + l16;
        bf16x8 v;
#pragma unroll
        for (int j = 0; j < 8; ++j) v[j] = f2bf(src[j * H_]);
        W2bf[idx] = v;
    } else {
        const int bid = blk - 544;
        const int li = threadIdx.x & 31;
        const int wi = threadIdx.x >> 5;
        const int b0 = (bid & 255) * 32;
        const int f0 = (bid >> 8) * 32;
#pragma unroll
        for (int r = wi; r < 32; r += 8)
            t[r][li] = x[(size_t)(b0 + r) * F_ + f0 + li];
        __syncthreads();
#pragma unroll
        for (int r = wi; r < 32; r += 8)
            xT[(size_t)(f0 + r) * B_ + b0 + li] = t[li][r];
    }
}

// ---- Main: persistent-A. Block = (f, b-chunk of 1024); wave = 256 b-rows (8 iters x 32).
// All weights (A-frags, W1, b1, b2, W3, b3) register-resident per wave, loaded ONCE.
// Per b-iter VMEM: 2 coalesced xT dwords + 2 atomics. h2^T = W2^T(64x128)*h1^T(128x32);
// C layout: col(lane&15)=batch, row=h -> epilogue h-reduction lane-local + 2 shfl.
__global__ __launch_bounds__(256, 2) void nam_mfma(
    const float* __restrict__ xT,       // [F,B]
    const float* __restrict__ W1,       // [F,S]
    const float* __restrict__ b1,       // [F,S]
    const bf16x8* __restrict__ W2bf,    // [F][4][4][64] frags
    const float* __restrict__ b2,       // [F,H]
    const float* __restrict__ W3,       // [F,H] (O=1)
    const float* __restrict__ b3,       // [F]
    float* __restrict__ out)            // [B]
{
    const int f     = blockIdx.x >> 3;      // 8 consecutive blocks share f
    const int chunk = blockIdx.x & 7;
    const int tid   = threadIdx.x;
    const int w     = tid >> 6;
    const int l     = tid & 63;
    const int l16   = l & 15;
    const int lg    = l >> 4;

    const int b0 = chunk * (B_ / NCHUNK) + w * 256;   // this wave's 256 b-rows

    // ---- one-time register-resident weight load ----
    const bf16x8* __restrict__ W2f = W2bf + (size_t)f * 16 * 64 + l;
    bf16x8 afrag[16];                                  // 64 VGPR
#pragma unroll
    for (int q = 0; q < 16; ++q) afrag[q] = W2f[q * 64];

    const float* __restrict__ W1f = W1 + f * S_;
    const float* __restrict__ b1f = b1 + f * S_;
    f32x4 w1r[8], b1r[8];                              // 64 VGPR (s = kk*32+lg*8+j)
#pragma unroll
    for (int kk = 0; kk < 4; ++kk) {
        w1r[kk * 2]     = *(const f32x4*)(W1f + kk * 32 + lg * 8);
        w1r[kk * 2 + 1] = *(const f32x4*)(W1f + kk * 32 + lg * 8 + 4);
        b1r[kk * 2]     = *(const f32x4*)(b1f + kk * 32 + lg * 8);
        b1r[kk * 2 + 1] = *(const f32x4*)(b1f + kk * 32 + lg * 8 + 4);
    }

    const float* __restrict__ b2f = b2 + f * H_;
    const float* __restrict__ W3f = W3 + f * H_;
    f32x4 b2v[4], w3v[4];                              // 32 VGPR (h = m*16+lg*4+r)
#pragma unroll
    for (int m = 0; m < 4; ++m) {
        b2v[m] = *(const f32x4*)(b2f + m * 16 + lg * 4);
        w3v[m] = *(const f32x4*)(W3f + m * 16 + lg * 4);
    }
    const float b3f = b3[f];
    const float* __restrict__ xTf = xT + (size_t)f * B_;

    // ---- b-loop: 8 iters x 32 b-rows; xv prefetched one iter ahead ----
    float xv0 = xTf[b0 + l16];
    float xv1 = xTf[b0 + 16 + l16];

#pragma unroll 1
    for (int it = 0; it < 8; ++it) {
        const int bbase = b0 + it * 32;
        float nx0 = 0.f, nx1 = 0.f;
        if (it < 7) {                                   // issue next xv early
            nx0 = xTf[bbase + 32 + l16];
            nx1 = xTf[bbase + 48 + l16];
        }

        f32x4 acc[4][2];
#pragma unroll
        for (int m = 0; m < 4; ++m) {
            acc[m][0] = (f32x4){0.f, 0.f, 0.f, 0.f};
            acc[m][1] = (f32x4){0.f, 0.f, 0.f, 0.f};
        }

#pragma unroll
        for (int kk = 0; kk < 4; ++kk) {
            bf16x8 bf0, bf1;                            // h1^T in bf16
#pragma unroll
            for (int j = 0; j < 4; ++j) {
                bf0[j]     = f2bf(fmaxf(fmaf(xv0, w1r[kk*2][j],     b1r[kk*2][j]),     0.f));
                bf0[j + 4] = f2bf(fmaxf(fmaf(xv0, w1r[kk*2+1][j],   b1r[kk*2+1][j]),   0.f));
                bf1[j]     = f2bf(fmaxf(fmaf(xv1, w1r[kk*2][j],     b1r[kk*2][j]),     0.f));
                bf1[j + 4] = f2bf(fmaxf(fmaf(xv1, w1r[kk*2+1][j],   b1r[kk*2+1][j]),   0.f));
            }
#pragma unroll
            for (int m = 0; m < 4; ++m) {
                acc[m][0] = __builtin_amdgcn_mfma_f32_16x16x32_bf16(afrag[kk*4+m], bf0, acc[m][0], 0, 0, 0);
                acc[m][1] = __builtin_amdgcn_mfma_f32_16x16x32_bf16(afrag[kk*4+m], bf1, acc[m][1], 0, 0, 0);
            }
        }

        // epilogue: fo[b] = sum_h relu(h2+b2)*W3 (+b3); lane h = m*16+lg*4+r
        float fo0 = 0.f, fo1 = 0.f;
#pragma unroll
        for (int m = 0; m < 4; ++m) {
#pragma unroll
            for (int r = 0; r < 4; ++r) {
                fo0 = fmaf(fmaxf(acc[m][0][r] + b2v[m][r], 0.f), w3v[m][r], fo0);
                fo1 = fmaf(fmaxf(acc[m][1][r] + b2v[m][r], 0.f), w3v[m][r], fo1);
            }
        }
        fo0 += __shfl_xor(fo0, 16);
        fo0 += __shfl_xor(fo0, 32);
        fo1 += __shfl_xor(fo1, 16);
        fo1 += __shfl_xor(fo1, 32);
        if (lg == 0) {
            atomicAdd(&out[bbase + l16], fo0 + b3f);
            atomicAdd(&out[bbase + 16 + l16], fo1 + b3f);
        }
        xv0 = nx0;
        xv1 = nx1;
    }
}

extern "C" void kernel_launch(void* const* d_in, const int* in_sizes, int n_in,
                              void* d_out, int out_size, void* d_ws, size_t ws_size,
                              hipStream_t stream) {
    const float* x    = (const float*)d_in[0];
    const float* W1   = (const float*)d_in[1];
    const float* b1   = (const float*)d_in[2];
    const float* W2   = (const float*)d_in[3];
    const float* b2   = (const float*)d_in[4];
    const float* W3   = (const float*)d_in[5];
    const float* b3   = (const float*)d_in[6];
    const float* bias = (const float*)d_in[7];
    float* out = (float*)d_out;

    bf16x8* W2bf = (bf16x8*)d_ws;                       // 2 MB: [F][4][4][64] frags
    const size_t W2BF_BYTES = (size_t)F_ * 16 * 64 * 16;
    float* xT = (float*)((char*)d_ws + W2BF_BYTES);     // 4 MB: [F][B]

    nam_prologue<<<32 + 512 + 1024, 256, 0, stream>>>(bias, out, W2, W2bf, x, xT);
    nam_mfma<<<F_ * NCHUNK, 256, 0, stream>>>(xT, W1, b1, W2bf, b2, W3, b3, out);
}